// Round 9
// baseline (1885.836 us; speedup 1.0000x reference)
//
#include <hip/hip_runtime.h>
#include <math.h>

#define NN 50000
#define NE 800000
#define NCOLS 1088   // 256 q | 256 k | 256 v | 256 qt | 64 skip   (cols are h*64+d order)

typedef long long i64;

// ---------------- non-temporal load/store helpers ----------------
static __device__ __forceinline__ float4 ntl4(const float4* p) {
  typedef float f4v __attribute__((ext_vector_type(4)));
  f4v v = __builtin_nontemporal_load((const f4v*)p);
  float4 r; r.x = v.x; r.y = v.y; r.z = v.z; r.w = v.w;
  return r;
}
static __device__ __forceinline__ void nts4(float4* p, float4 a) {
  typedef float f4v __attribute__((ext_vector_type(4)));
  f4v v; v.x = a.x; v.y = a.y; v.z = a.z; v.w = a.w;
  __builtin_nontemporal_store(v, (f4v*)p);
}
static __device__ __forceinline__ void nts2(float* p, float a, float b) {
  typedef float f2v __attribute__((ext_vector_type(2)));
  f2v v; v.x = a; v.y = b;
  __builtin_nontemporal_store(v, (f2v*)p);
}

// ---------------- edge-index dtype probe + extraction ----------------
__global__ void detect_i64(const int* __restrict__ ei32, int* __restrict__ flag) {
  int i = blockIdx.x * blockDim.x + threadIdx.x;
  if (i < 2048) {
    if (ei32[2 * i + 1] != 0) atomicOr(flag, 1);  // 1 -> data is int32
  }
}

__global__ void extract_edges(const void* __restrict__ ei, const int* __restrict__ flag,
                              int* __restrict__ src32, int* __restrict__ dst32, int ne) {
  int is32 = *flag;
  int i = blockIdx.x * blockDim.x + threadIdx.x;
  int st = gridDim.x * blockDim.x;
  if (is32) {
    const int* p = (const int*)ei;
    for (; i < ne; i += st) { src32[i] = p[i]; dst32[i] = p[ne + i]; }
  } else {
    const i64* p = (const i64*)ei;
    for (; i < ne; i += st) { src32[i] = (int)p[i]; dst32[i] = (int)p[ne + i]; }
  }
}

// ---------------- CSR build ----------------
__global__ void hist_kernel(const int* __restrict__ dst, int* __restrict__ deg, int ne) {
  int i = blockIdx.x * blockDim.x + threadIdx.x;
  int st = gridDim.x * blockDim.x;
  for (; i < ne; i += st) atomicAdd(&deg[dst[i]], 1);
}

// Parallel 2-level scan
#define SCHUNK 1024
__global__ void scanA(const int* __restrict__ deg, int* __restrict__ row_ptr,
                      int* __restrict__ csum, int n) {
  __shared__ int buf[SCHUNK];
  int c = blockIdx.x, t = threadIdx.x;
  int idx = c * SCHUNK + t;
  int v = (idx < n) ? deg[idx] : 0;
  buf[t] = v;
  __syncthreads();
  for (int off = 1; off < SCHUNK; off <<= 1) {
    int x = (t >= off) ? buf[t - off] : 0;
    __syncthreads();
    buf[t] += x;
    __syncthreads();
  }
  if (idx < n) row_ptr[idx + 1] = buf[t];
  if (t == SCHUNK - 1) csum[c] = buf[t];
}

__global__ void scanB(int* __restrict__ csum, int nchunks) {
  if (threadIdx.x == 0 && blockIdx.x == 0) {
    int run = 0;
    for (int c = 0; c < nchunks; ++c) { int v = csum[c]; csum[c] = run; run += v; }
  }
}

__global__ void scanC(int* __restrict__ row_ptr, const int* __restrict__ csum, int n) {
  int c = blockIdx.x, t = threadIdx.x;
  int idx = c * SCHUNK + t;
  if (idx < n) row_ptr[idx + 1] += csum[c];
  if (idx == 0) row_ptr[0] = 0;
}

__global__ void scatter_kernel(const int* __restrict__ src, const int* __restrict__ dst,
                               const int* __restrict__ row_ptr, int* __restrict__ cursor,
                               int* __restrict__ src_sorted, int* __restrict__ eid_sorted, int ne) {
  int i = blockIdx.x * blockDim.x + threadIdx.x;
  int st = gridDim.x * blockDim.x;
  for (; i < ne; i += st) {
    int d = dst[i];
    int pos = row_ptr[d] + atomicAdd(&cursor[d], 1);
    src_sorted[pos] = src[i];
    eid_sorted[pos] = i;
  }
}

// Deterministic order: sort each node's edge list by eid.
__global__ void sort_lists(const int* __restrict__ row_ptr, int* __restrict__ src_sorted,
                           int* __restrict__ eid_sorted, int n) {
  int node = blockIdx.x * blockDim.x + threadIdx.x;
  if (node >= n) return;
  int beg = row_ptr[node], end = row_ptr[node + 1];
  for (int a = beg + 1; a < end; ++a) {
    int e = eid_sorted[a], s = src_sorted[a];
    int b = a - 1;
    while (b >= beg && eid_sorted[b] > e) {
      eid_sorted[b + 1] = eid_sorted[b];
      src_sorted[b + 1] = src_sorted[b];
      --b;
    }
    eid_sorted[b + 1] = e; src_sorted[b + 1] = s;
  }
}

// ---------------- ea pre-gather into CSR order (nt both sides) ----------
__global__ void ea_gather(const int* __restrict__ eid_sorted, const float* __restrict__ ea,
                          float* __restrict__ ea_csr, int ne) {
  long total = (long)ne * 16;
  long st = (long)gridDim.x * blockDim.x;
  for (long i = (long)blockIdx.x * blockDim.x + threadIdx.x; i < total; i += st) {
    int j = (int)(i >> 4);
    int c = (int)(i & 15);
    int e = eid_sorted[j];
    float4 v = ntl4(((const float4*)ea) + (size_t)e * 16 + c);
    nts4(((float4*)ea_csr) + i, v);
  }
}

// ---------------- weight prep (fp32, head-major cols) ----------------
__global__ void prep_wt(const float* __restrict__ Wq, const float* __restrict__ Wk,
                        const float* __restrict__ Wv, const float* __restrict__ We,
                        const float* __restrict__ Wsk, float* __restrict__ Wt, int fin) {
  int i = blockIdx.x * blockDim.x + threadIdx.x;
  if (i >= NCOLS * fin) return;
  int col = i / fin, k = i % fin;
  float val;
  if (col < 768) {
    const float* W = (col < 256) ? Wq : (col < 512) ? Wk : Wv;
    val = W[k * 256 + (col & 255)];
  } else if (col < 1024) {
    int idx = col - 768; int h = idx >> 6, ce = idx & 63;
    float a = 0.f;
    for (int d = 0; d < 64; ++d) a += Wq[k * 256 + h * 64 + d] * We[ce * 256 + h * 64 + d];
    val = a;
  } else {
    val = Wsk[k * 64 + (col - 1024)];
  }
  Wt[(size_t)col * fin + k] = val;
}

__global__ void prep_bias(const float* __restrict__ bq, const float* __restrict__ bk,
                          const float* __restrict__ bv, const float* __restrict__ We,
                          const float* __restrict__ bsk, float* __restrict__ bb) {
  int col = blockIdx.x * blockDim.x + threadIdx.x;
  if (col >= NCOLS) return;
  float val;
  if (col < 768) {
    const float* b = (col < 256) ? bq : (col < 512) ? bk : bv;
    val = b[col & 255];
  } else if (col < 1024) {
    int idx = col - 768; int h = idx >> 6, ce = idx & 63;
    float a = 0.f;
    for (int d = 0; d < 64; ++d) a += bq[h * 64 + d] * We[ce * 256 + h * 64 + d];
    val = a;
  } else {
    val = bsk[col - 1024];
  }
  bb[col] = val;
}

// ---------------- fp32 node GEMM: out = X[N,fin] @ Wt^T + b ----------------
__global__ __launch_bounds__(256) void node_gemm_f32(
    const float* __restrict__ X, const float* __restrict__ Wt, const float* __restrict__ bb,
    float* __restrict__ qq_tab, float* __restrict__ kv_tab,
    float* __restrict__ skip_tab, int n, int fin) {
  __shared__ __align__(16) float Xs[128][68];
  __shared__ __align__(16) float Ws[64][68];
  int tid = threadIdx.x;
  int tx = tid & 15, ty = tid >> 4;
  int m0 = blockIdx.x * 128, c0 = blockIdx.y * 64;
  float acc[8][4];
  #pragma unroll
  for (int i = 0; i < 8; ++i)
    #pragma unroll
    for (int j = 0; j < 4; ++j) acc[i][j] = 0.f;

  for (int k0 = 0; k0 < fin; k0 += 64) {
    #pragma unroll
    for (int p = 0; p < 8; ++p) {
      int r = ty + 16 * p;
      float4 xv = make_float4(0.f, 0.f, 0.f, 0.f);
      if (m0 + r < n) xv = *(const float4*)&X[(size_t)(m0 + r) * fin + k0 + tx * 4];
      *(float4*)&Xs[r][tx * 4] = xv;
    }
    #pragma unroll
    for (int p = 0; p < 4; ++p) {
      int r = ty + 16 * p;
      float4 wv = *(const float4*)&Wt[(size_t)(c0 + r) * fin + k0 + tx * 4];
      *(float4*)&Ws[r][tx * 4] = wv;
    }
    __syncthreads();
    #pragma unroll 4
    for (int kk = 0; kk < 64; kk += 4) {
      float4 a[8], b[4];
      #pragma unroll
      for (int i = 0; i < 8; ++i) a[i] = *(const float4*)&Xs[ty + 16 * i][kk];
      #pragma unroll
      for (int j = 0; j < 4; ++j) b[j] = *(const float4*)&Ws[tx + 16 * j][kk];
      #pragma unroll
      for (int i = 0; i < 8; ++i)
        #pragma unroll
        for (int j = 0; j < 4; ++j) {
          acc[i][j] = fmaf(a[i].x, b[j].x, acc[i][j]);
          acc[i][j] = fmaf(a[i].y, b[j].y, acc[i][j]);
          acc[i][j] = fmaf(a[i].z, b[j].z, acc[i][j]);
          acc[i][j] = fmaf(a[i].w, b[j].w, acc[i][j]);
        }
    }
    __syncthreads();
  }
  #pragma unroll
  for (int j = 0; j < 4; ++j) {
    int col = c0 + tx + 16 * j;
    float bias = bb[col];
    #pragma unroll
    for (int i = 0; i < 8; ++i) {
      int row = m0 + ty + 16 * i;
      if (row >= n) continue;
      float val = acc[i][j] + bias;
      if (col < 256)        qq_tab[(size_t)row * 512 + col] = val;          // q
      else if (col < 768)   kv_tab[(size_t)row * 512 + col - 256] = val;    // k | v
      else if (col < 1024)  qq_tab[(size_t)row * 512 + col - 512] = val;    // qt
      else                  skip_tab[(size_t)row * 64 + col - 1024] = val;
    }
  }
}

// ---------------- fused attention v5: 2 nodes/wave, nt streams, 2-deep pipeline ----------------
// lane = half*32 + h*8 + c8. Lane owns 8 channels (2 float4) of head h.
__global__ __launch_bounds__(256) void attn_kernel_v5(
    const int* __restrict__ row_ptr, const int* __restrict__ src_sorted,
    const int* __restrict__ eid_sorted, const float* __restrict__ ea,
    const float* __restrict__ ea_csr, int use_csr,
    const float* __restrict__ qq_tab, const float* __restrict__ kv_tab,
    const float* __restrict__ skip_tab, const float* __restrict__ west,  // = We [64][256]
    const float* __restrict__ gnw, const float* __restrict__ gnb,
    float* __restrict__ out, int n) {
  int tid = threadIdx.x;
  int wave = tid >> 6, lane = tid & 63;
  int half = lane >> 5, h = (lane >> 3) & 3, c8 = lane & 7;
  int ko = h * 16 + c8 * 2;      // float4 offset of this lane's channel chunk in a 256-f row
  int eo = c8 * 2;               // float4 offset in a 64-float ea row
  const float4* qq4 = (const float4*)qq_tab;
  const float4* kv4 = (const float4*)kv_tab;
  const float4* e4p = (const float4*)ea;
  const float4* ec4 = (const float4*)ea_csr;
  const float4* w4p = (const float4*)west;

  int node = blockIdx.x * 8 + wave * 2 + half;
  int beg = 0, deg = 0;
  if (node < n) {
    beg = row_ptr[node];
    deg = row_ptr[node + 1] - beg;
  } else {
    node = -1;
  }
  int tmax = deg;
  { int o = __shfl_xor(tmax, 32); tmax = o > tmax ? o : tmax; }

  float4 q4a = make_float4(0.f,0.f,0.f,0.f), q4b = q4a, t4a = q4a, t4b = q4a;
  if (node >= 0) {
    q4a = ntl4(&qq4[(size_t)node * 128 + ko]);
    q4b = ntl4(&qq4[(size_t)node * 128 + ko + 1]);
    t4a = ntl4(&qq4[(size_t)node * 128 + 64 + ko]);
    t4b = ntl4(&qq4[(size_t)node * 128 + 64 + ko + 1]);
  }

  float m = -INFINITY, s = 0.f;
  float4 av0 = make_float4(0.f,0.f,0.f,0.f), av1 = av0, aw0 = av0, aw1 = av0;

  // kv loads: normal (cached — the reused table). E loads: nt (read-once stream).
#define LOADP(jdx, K0r, K1r, V0r, V1r, E0r, E1r)              \
  {                                                           \
    int jc = (jdx); if (jc > NE - 1) jc = NE - 1;             \
    int s_ = src_sorted[jc];                                  \
    const float4* kr = kv4 + (size_t)s_ * 128;                \
    K0r = kr[ko]; K1r = kr[ko + 1];                           \
    V0r = kr[64 + ko]; V1r = kr[64 + ko + 1];                 \
    if (use_csr) {                                            \
      const float4* er = ec4 + (size_t)jc * 16;               \
      E0r = ntl4(er + eo); E1r = ntl4(er + eo + 1);           \
    } else {                                                  \
      int e_ = eid_sorted[jc];                                \
      const float4* er = e4p + (size_t)e_ * 16;               \
      E0r = ntl4(er + eo); E1r = ntl4(er + eo + 1);           \
    }                                                         \
  }

#define SCORE_ONLINE(tt, K0, K1, V0, V1, E0, E1)              \
  {                                                           \
    float p = q4a.x * K0.x + q4a.y * K0.y + q4a.z * K0.z + q4a.w * K0.w; \
    p = fmaf(q4b.x, K1.x, p); p = fmaf(q4b.y, K1.y, p);       \
    p = fmaf(q4b.z, K1.z, p); p = fmaf(q4b.w, K1.w, p);       \
    p = fmaf(t4a.x, E0.x, p); p = fmaf(t4a.y, E0.y, p);       \
    p = fmaf(t4a.z, E0.z, p); p = fmaf(t4a.w, E0.w, p);       \
    p = fmaf(t4b.x, E1.x, p); p = fmaf(t4b.y, E1.y, p);       \
    p = fmaf(t4b.z, E1.z, p); p = fmaf(t4b.w, E1.w, p);       \
    p += __shfl_xor(p, 1);                                    \
    p += __shfl_xor(p, 2);                                    \
    p += __shfl_xor(p, 4);                                    \
    p *= 0.125f;                                              \
    bool valid = ((tt) < deg);                                \
    float d_ = p - m;                                         \
    float e_ = __expf(-fabsf(d_));                            \
    float sc = (valid && d_ > 0.f) ? e_ : 1.f;                \
    float pp = valid ? ((d_ > 0.f) ? 1.f : e_) : 0.f;         \
    if (valid) m = fmaxf(m, p);                               \
    s = s * sc + pp;                                          \
    av0.x = av0.x * sc + pp * V0.x; av0.y = av0.y * sc + pp * V0.y; \
    av0.z = av0.z * sc + pp * V0.z; av0.w = av0.w * sc + pp * V0.w; \
    av1.x = av1.x * sc + pp * V1.x; av1.y = av1.y * sc + pp * V1.y; \
    av1.z = av1.z * sc + pp * V1.z; av1.w = av1.w * sc + pp * V1.w; \
    aw0.x = aw0.x * sc + pp * E0.x; aw0.y = aw0.y * sc + pp * E0.y; \
    aw0.z = aw0.z * sc + pp * E0.z; aw0.w = aw0.w * sc + pp * E0.w; \
    aw1.x = aw1.x * sc + pp * E1.x; aw1.y = aw1.y * sc + pp * E1.y; \
    aw1.z = aw1.z * sc + pp * E1.z; aw1.w = aw1.w * sc + pp * E1.w; \
  }

  float4 KA0, KA1, VA0, VA1, EA0, EA1;
  float4 KB0, KB1, VB0, VB1, EB0, EB1;
  LOADP(beg + 0, KA0, KA1, VA0, VA1, EA0, EA1);
  LOADP(beg + 1, KB0, KB1, VB0, VB1, EB0, EB1);

  for (int t = 0; t < tmax; t += 2) {
    {
      float4 nK0, nK1, nV0, nV1, nE0, nE1;
      LOADP(beg + t + 2, nK0, nK1, nV0, nV1, nE0, nE1);
      SCORE_ONLINE(t, KA0, KA1, VA0, VA1, EA0, EA1);
      KA0 = nK0; KA1 = nK1; VA0 = nV0; VA1 = nV1; EA0 = nE0; EA1 = nE1;
    }
    if (t + 1 < tmax) {   // tmax is wave-uniform
      float4 nK0, nK1, nV0, nV1, nE0, nE1;
      LOADP(beg + t + 3, nK0, nK1, nV0, nV1, nE0, nE1);
      SCORE_ONLINE(t + 1, KB0, KB1, VB0, VB1, EB0, EB1);
      KB0 = nK0; KB1 = nK1; VB0 = nV0; VB1 = nV1; EB0 = nE0; EB1 = nE1;
    }
  }

  float inv = s > 0.f ? 1.f / s : 0.f;
  float4 avn0 = make_float4(av0.x*inv, av0.y*inv, av0.z*inv, av0.w*inv);
  float4 avn1 = make_float4(av1.x*inv, av1.y*inv, av1.z*inv, av1.w*inv);
  float4 awn0 = make_float4(aw0.x*inv, aw0.y*inv, aw0.z*inv, aw0.w*inv);
  float4 awn1 = make_float4(aw1.x*inv, aw1.y*inv, aw1.z*inv, aw1.w*inv);

  // West matvec: post[h][lane's 8 channels] = sum_ce awn[h][ce] * We[ce][h*64 + d]
  float4 post0 = make_float4(0.f,0.f,0.f,0.f), post1 = post0;
  int lbase = lane & 0x38;   // preserve half|h bits
  #pragma unroll
  for (int cc4 = 0; cc4 < 16; ++cc4) {
    float4 srcv = (cc4 & 1) ? awn1 : awn0;
    int sl = lbase | (cc4 >> 1);
    float wa = __shfl(srcv.x, sl);
    float wb = __shfl(srcv.y, sl);
    float wc = __shfl(srcv.z, sl);
    float wd = __shfl(srcv.w, sl);
    const float4* wr = w4p + (size_t)(cc4 * 4) * 64 + ko;
    float4 wA0 = wr[0],   wA1 = wr[1];
    float4 wB0 = wr[64],  wB1 = wr[65];
    float4 wC0 = wr[128], wC1 = wr[129];
    float4 wD0 = wr[192], wD1 = wr[193];
    post0.x = fmaf(wa, wA0.x, post0.x); post0.y = fmaf(wa, wA0.y, post0.y);
    post0.z = fmaf(wa, wA0.z, post0.z); post0.w = fmaf(wa, wA0.w, post0.w);
    post1.x = fmaf(wa, wA1.x, post1.x); post1.y = fmaf(wa, wA1.y, post1.y);
    post1.z = fmaf(wa, wA1.z, post1.z); post1.w = fmaf(wa, wA1.w, post1.w);
    post0.x = fmaf(wb, wB0.x, post0.x); post0.y = fmaf(wb, wB0.y, post0.y);
    post0.z = fmaf(wb, wB0.z, post0.z); post0.w = fmaf(wb, wB0.w, post0.w);
    post1.x = fmaf(wb, wB1.x, post1.x); post1.y = fmaf(wb, wB1.y, post1.y);
    post1.z = fmaf(wb, wB1.z, post1.z); post1.w = fmaf(wb, wB1.w, post1.w);
    post0.x = fmaf(wc, wC0.x, post0.x); post0.y = fmaf(wc, wC0.y, post0.y);
    post0.z = fmaf(wc, wC0.z, post0.z); post0.w = fmaf(wc, wC0.w, post0.w);
    post1.x = fmaf(wc, wC1.x, post1.x); post1.y = fmaf(wc, wC1.y, post1.y);
    post1.z = fmaf(wc, wC1.z, post1.z); post1.w = fmaf(wc, wC1.w, post1.w);
    post0.x = fmaf(wd, wD0.x, post0.x); post0.y = fmaf(wd, wD0.y, post0.y);
    post0.z = fmaf(wd, wD0.z, post0.z); post0.w = fmaf(wd, wD0.w, post0.w);
    post1.x = fmaf(wd, wD1.x, post1.x); post1.y = fmaf(wd, wD1.y, post1.y);
    post1.z = fmaf(wd, wD1.z, post1.z); post1.w = fmaf(wd, wD1.w, post1.w);
  }

  float4 tot0 = make_float4(avn0.x+post0.x, avn0.y+post0.y, avn0.z+post0.z, avn0.w+post0.w);
  float4 tot1 = make_float4(avn1.x+post1.x, avn1.y+post1.y, avn1.z+post1.z, avn1.w+post1.w);
  // head-sum (lanes with same c8, different h): xor 8, 16 (stays within half)
  tot0.x += __shfl_xor(tot0.x, 8);  tot0.y += __shfl_xor(tot0.y, 8);
  tot0.z += __shfl_xor(tot0.z, 8);  tot0.w += __shfl_xor(tot0.w, 8);
  tot1.x += __shfl_xor(tot1.x, 8);  tot1.y += __shfl_xor(tot1.y, 8);
  tot1.z += __shfl_xor(tot1.z, 8);  tot1.w += __shfl_xor(tot1.w, 8);
  tot0.x += __shfl_xor(tot0.x, 16); tot0.y += __shfl_xor(tot0.y, 16);
  tot0.z += __shfl_xor(tot0.z, 16); tot0.w += __shfl_xor(tot0.w, 16);
  tot1.x += __shfl_xor(tot1.x, 16); tot1.y += __shfl_xor(tot1.y, 16);
  tot1.z += __shfl_xor(tot1.z, 16); tot1.w += __shfl_xor(tot1.w, 16);

  if (node >= 0) {
    const float4* skr = (const float4*)(skip_tab + (size_t)node * 64);
    float4 sk0 = ntl4(&skr[c8 * 2]), sk1 = ntl4(&skr[c8 * 2 + 1]);
    const float4* gwr = (const float4*)gnw;
    const float4* gbr = (const float4*)gnb;
    float4 gw0 = gwr[c8 * 2], gw1 = gwr[c8 * 2 + 1];
    float4 gb0 = gbr[c8 * 2], gb1 = gbr[c8 * 2 + 1];
    // group A = channels c8*8+0..3, group B = +4..7 — lane-local GN
    float a0 = 0.25f * tot0.x + sk0.x, a1 = 0.25f * tot0.y + sk0.y;
    float a2 = 0.25f * tot0.z + sk0.z, a3 = 0.25f * tot0.w + sk0.w;
    float b0 = 0.25f * tot1.x + sk1.x, b1 = 0.25f * tot1.y + sk1.y;
    float b2 = 0.25f * tot1.z + sk1.z, b3 = 0.25f * tot1.w + sk1.w;
    float muA = ((a0 + a1) + (a2 + a3)) * 0.25f;
    float muB = ((b0 + b1) + (b2 + b3)) * 0.25f;
    float dA0 = a0-muA, dA1 = a1-muA, dA2 = a2-muA, dA3 = a3-muA;
    float dB0 = b0-muB, dB1 = b1-muB, dB2 = b2-muB, dB3 = b3-muB;
    float vA = ((dA0*dA0 + dA1*dA1) + (dA2*dA2 + dA3*dA3)) * 0.25f;
    float vB = ((dB0*dB0 + dB1*dB1) + (dB2*dB2 + dB3*dB3)) * 0.25f;
    float rA = rsqrtf(vA + 1e-5f), rB = rsqrtf(vB + 1e-5f);
    float yA0 = dA0*rA*gw0.x + gb0.x, yA1 = dA1*rA*gw0.y + gb0.y;
    float yA2 = dA2*rA*gw0.z + gb0.z, yA3 = dA3*rA*gw0.w + gb0.w;
    float yB0 = dB0*rB*gw1.x + gb1.x, yB1 = dB1*rB*gw1.y + gb1.y;
    float yB2 = dB2*rB*gw1.z + gb1.z, yB3 = dB3*rB*gw1.w + gb1.w;
    #define GELU(y) (0.5f * (y) * (1.0f + erff((y) * 0.70710678118654752f)))
    float gA0 = GELU(yA0), gA1 = GELU(yA1), gA2 = GELU(yA2), gA3 = GELU(yA3);
    float gB0 = GELU(yB0), gB1 = GELU(yB1), gB2 = GELU(yB2), gB3 = GELU(yB3);
    // lane writes channels c8*8 + h*2 + {0,1}
    float ox, oy;
    if (h == 0)      { ox = gA0; oy = gA1; }
    else if (h == 1) { ox = gA2; oy = gA3; }
    else if (h == 2) { ox = gB0; oy = gB1; }
    else             { ox = gB2; oy = gB3; }
    nts2(out + (size_t)node * 64 + c8 * 8 + h * 2, ox, oy);
  }
}

// ---------------- host ----------------
extern "C" void kernel_launch(void* const* d_in, const int* in_sizes, int n_in,
                              void* d_out, int out_size, void* d_ws, size_t ws_size,
                              hipStream_t stream) {
  (void)in_sizes; (void)n_in;
  const float* x = (const float*)d_in[0];
  const void* ei = d_in[1];
  const float* ea = (const float*)d_in[2];
  const float *Wq[3], *bq[3], *Wk[3], *bk[3], *Wv[3], *bv[3], *We[3], *Wsk[3], *bsk[3];
  for (int L = 0; L < 3; ++L) {
    int b = 3 + 9 * L;
    Wq[L] = (const float*)d_in[b + 0]; bq[L] = (const float*)d_in[b + 1];
    Wk[L] = (const float*)d_in[b + 2]; bk[L] = (const float*)d_in[b + 3];
    Wv[L] = (const float*)d_in[b + 4]; bv[L] = (const float*)d_in[b + 5];
    We[L] = (const float*)d_in[b + 6]; Wsk[L] = (const float*)d_in[b + 7];
    bsk[L] = (const float*)d_in[b + 8];
  }
  const float* gnw = (const float*)d_in[30];
  const float* gnb = (const float*)d_in[31];

  char* p = (char*)d_ws;
  auto alloc = [&](size_t bytes) -> void* {
    void* r = (void*)p;
    p += (bytes + 255) & ~(size_t)255;
    return r;
  };
  float* qq_tab = (float*)alloc((size_t)NN * 512 * 4);
  float* kv_tab = (float*)alloc((size_t)NN * 512 * 4);
  float* skip_tab = (float*)alloc((size_t)NN * 64 * 4);
  float* h_buf = (float*)alloc((size_t)NN * 64 * 4);
  int* row_ptr = (int*)alloc((size_t)(NN + 1) * 4);
  int* deg = (int*)alloc((size_t)NN * 4);
  int* cursor = (int*)alloc((size_t)NN * 4);
  int* csum = (int*)alloc(1024 * 4);
  int* src_sorted = (int*)alloc((size_t)NE * 4);
  int* eid_sorted = (int*)alloc((size_t)NE * 4);
  int* src32 = (int*)alloc((size_t)NE * 4);
  int* dst32 = (int*)alloc((size_t)NE * 4);
  int* flag = (int*)alloc(256);
  float* Wt[3]; float* bb[3];
  Wt[0] = (float*)alloc((size_t)NCOLS * 128 * 4);
  Wt[1] = (float*)alloc((size_t)NCOLS * 64 * 4);
  Wt[2] = (float*)alloc((size_t)NCOLS * 64 * 4);
  for (int L = 0; L < 3; ++L) bb[L] = (float*)alloc((size_t)NCOLS * 4);

  // Workspace overflow guard on the REQUIRED buffers:
  // all-zero output == error 1.65625 signature.
  if ((size_t)(p - (char*)d_ws) > ws_size) {
    hipMemsetAsync(d_out, 0, (size_t)out_size * 4, stream);
    return;
  }

  // Optional ea_csr buffer (205 MB): streamed ea reads in the attn loop.
  float* ea_csr = nullptr;
  int use_csr = 0;
  {
    size_t need = (size_t)(p - (char*)d_ws) + (size_t)NE * 64 * 4 + 256;
    if (need <= ws_size) {
      ea_csr = (float*)alloc((size_t)NE * 64 * 4);
      use_csr = 1;
    }
  }

  hipMemsetAsync(deg, 0, (size_t)NN * 4, stream);
  hipMemsetAsync(cursor, 0, (size_t)NN * 4, stream);
  hipMemsetAsync(flag, 0, 4, stream);

  detect_i64<<<8, 256, 0, stream>>>((const int*)ei, flag);
  extract_edges<<<2048, 256, 0, stream>>>(ei, flag, src32, dst32, NE);

  hist_kernel<<<2048, 256, 0, stream>>>(dst32, deg, NE);
  int nchunks = (NN + SCHUNK - 1) / SCHUNK;
  scanA<<<nchunks, SCHUNK, 0, stream>>>(deg, row_ptr, csum, NN);
  scanB<<<1, 64, 0, stream>>>(csum, nchunks);
  scanC<<<nchunks, SCHUNK, 0, stream>>>(row_ptr, csum, NN);
  scatter_kernel<<<2048, 256, 0, stream>>>(src32, dst32, row_ptr, cursor, src_sorted, eid_sorted, NE);
  sort_lists<<<(NN + 255) / 256, 256, 0, stream>>>(row_ptr, src_sorted, eid_sorted, NN);
  if (use_csr)
    ea_gather<<<2048, 256, 0, stream>>>(eid_sorted, ea, ea_csr, NE);

  for (int L = 0; L < 3; ++L) {
    int fin = (L == 0) ? 128 : 64;
    prep_wt<<<(NCOLS * fin + 255) / 256, 256, 0, stream>>>(Wq[L], Wk[L], Wv[L], We[L], Wsk[L], Wt[L], fin);
    prep_bias<<<(NCOLS + 255) / 256, 256, 0, stream>>>(bq[L], bk[L], bv[L], We[L], bsk[L], bb[L]);
  }

  const float* hin = x;
  int nblk = (NN + 7) / 8;
  for (int L = 0; L < 3; ++L) {
    int fin = (L == 0) ? 128 : 64;
    dim3 g((NN + 127) / 128, 17);
    node_gemm_f32<<<g, 256, 0, stream>>>(hin, Wt[L], bb[L], qq_tab, kv_tab, skip_tab, NN, fin);
    attn_kernel_v5<<<nblk, 256, 0, stream>>>(
        row_ptr, src_sorted, eid_sorted, ea, ea_csr, use_csr, qq_tab, kv_tab,
        skip_tab, We[L], gnw, gnb,
        (L == 2) ? (float*)d_out : h_buf, NN);
    hin = h_buf;
  }
}

// Round 10
// 1760.893 us; speedup vs baseline: 1.0710x; 1.0710x over previous
//
#include <hip/hip_runtime.h>
#include <math.h>

#define NN 50000
#define NE 800000
#define NCOLS 1088   // 256 q | 256 k | 256 v | 256 qt | 64 skip   (cols are h*64+d order)

typedef long long i64;

// ---------------- edge-index dtype probe + extraction ----------------
__global__ void detect_i64(const int* __restrict__ ei32, int* __restrict__ flag) {
  int i = blockIdx.x * blockDim.x + threadIdx.x;
  if (i < 2048) {
    if (ei32[2 * i + 1] != 0) atomicOr(flag, 1);  // 1 -> data is int32
  }
}

__global__ void extract_edges(const void* __restrict__ ei, const int* __restrict__ flag,
                              int* __restrict__ src32, int* __restrict__ dst32, int ne) {
  int is32 = *flag;
  int i = blockIdx.x * blockDim.x + threadIdx.x;
  int st = gridDim.x * blockDim.x;
  if (is32) {
    const int* p = (const int*)ei;
    for (; i < ne; i += st) { src32[i] = p[i]; dst32[i] = p[ne + i]; }
  } else {
    const i64* p = (const i64*)ei;
    for (; i < ne; i += st) { src32[i] = (int)p[i]; dst32[i] = (int)p[ne + i]; }
  }
}

// ---------------- CSR build ----------------
__global__ void hist_kernel(const int* __restrict__ dst, int* __restrict__ deg, int ne) {
  int i = blockIdx.x * blockDim.x + threadIdx.x;
  int st = gridDim.x * blockDim.x;
  for (; i < ne; i += st) atomicAdd(&deg[dst[i]], 1);
}

#define SCHUNK 1024
__global__ void scanA(const int* __restrict__ deg, int* __restrict__ row_ptr,
                      int* __restrict__ csum, int n) {
  __shared__ int buf[SCHUNK];
  int c = blockIdx.x, t = threadIdx.x;
  int idx = c * SCHUNK + t;
  int v = (idx < n) ? deg[idx] : 0;
  buf[t] = v;
  __syncthreads();
  for (int off = 1; off < SCHUNK; off <<= 1) {
    int x = (t >= off) ? buf[t - off] : 0;
    __syncthreads();
    buf[t] += x;
    __syncthreads();
  }
  if (idx < n) row_ptr[idx + 1] = buf[t];
  if (t == SCHUNK - 1) csum[c] = buf[t];
}

__global__ void scanB(int* __restrict__ csum, int nchunks) {
  if (threadIdx.x == 0 && blockIdx.x == 0) {
    int run = 0;
    for (int c = 0; c < nchunks; ++c) { int v = csum[c]; csum[c] = run; run += v; }
  }
}

__global__ void scanC(int* __restrict__ row_ptr, const int* __restrict__ csum, int n) {
  int c = blockIdx.x, t = threadIdx.x;
  int idx = c * SCHUNK + t;
  if (idx < n) row_ptr[idx + 1] += csum[c];
  if (idx == 0) row_ptr[0] = 0;
}

__global__ void scatter_kernel(const int* __restrict__ src, const int* __restrict__ dst,
                               const int* __restrict__ row_ptr, int* __restrict__ cursor,
                               int* __restrict__ src_sorted, int* __restrict__ eid_sorted, int ne) {
  int i = blockIdx.x * blockDim.x + threadIdx.x;
  int st = gridDim.x * blockDim.x;
  for (; i < ne; i += st) {
    int d = dst[i];
    int pos = row_ptr[d] + atomicAdd(&cursor[d], 1);
    src_sorted[pos] = src[i];
    eid_sorted[pos] = i;
  }
}

// Deterministic order: sort each node's edge list by eid.
__global__ void sort_lists(const int* __restrict__ row_ptr, int* __restrict__ src_sorted,
                           int* __restrict__ eid_sorted, int n) {
  int node = blockIdx.x * blockDim.x + threadIdx.x;
  if (node >= n) return;
  int beg = row_ptr[node], end = row_ptr[node + 1];
  for (int a = beg + 1; a < end; ++a) {
    int e = eid_sorted[a], s = src_sorted[a];
    int b = a - 1;
    while (b >= beg && eid_sorted[b] > e) {
      eid_sorted[b + 1] = eid_sorted[b];
      src_sorted[b + 1] = src_sorted[b];
      --b;
    }
    eid_sorted[b + 1] = e; src_sorted[b + 1] = s;
  }
}

// ---------------- ea pre-gather into CSR order ----------
__global__ void ea_gather(const int* __restrict__ eid_sorted, const float* __restrict__ ea,
                          float* __restrict__ ea_csr, int ne) {
  long total = (long)ne * 16;
  long st = (long)gridDim.x * blockDim.x;
  for (long i = (long)blockIdx.x * blockDim.x + threadIdx.x; i < total; i += st) {
    int j = (int)(i >> 4);
    int c = (int)(i & 15);
    int e = eid_sorted[j];
    ((float4*)ea_csr)[i] = ((const float4*)ea)[(size_t)e * 16 + c];
  }
}

// ---------------- weight prep (fp32, head-major cols) ----------------
__global__ void prep_wt(const float* __restrict__ Wq, const float* __restrict__ Wk,
                        const float* __restrict__ Wv, const float* __restrict__ We,
                        const float* __restrict__ Wsk, float* __restrict__ Wt, int fin) {
  int i = blockIdx.x * blockDim.x + threadIdx.x;
  if (i >= NCOLS * fin) return;
  int col = i / fin, k = i % fin;
  float val;
  if (col < 768) {
    const float* W = (col < 256) ? Wq : (col < 512) ? Wk : Wv;
    val = W[k * 256 + (col & 255)];
  } else if (col < 1024) {
    int idx = col - 768; int h = idx >> 6, ce = idx & 63;
    float a = 0.f;
    for (int d = 0; d < 64; ++d) a += Wq[k * 256 + h * 64 + d] * We[ce * 256 + h * 64 + d];
    val = a;
  } else {
    val = Wsk[k * 64 + (col - 1024)];
  }
  Wt[(size_t)col * fin + k] = val;
}

__global__ void prep_bias(const float* __restrict__ bq, const float* __restrict__ bk,
                          const float* __restrict__ bv, const float* __restrict__ We,
                          const float* __restrict__ bsk, float* __restrict__ bb) {
  int col = blockIdx.x * blockDim.x + threadIdx.x;
  if (col >= NCOLS) return;
  float val;
  if (col < 768) {
    const float* b = (col < 256) ? bq : (col < 512) ? bk : bv;
    val = b[col & 255];
  } else if (col < 1024) {
    int idx = col - 768; int h = idx >> 6, ce = idx & 63;
    float a = 0.f;
    for (int d = 0; d < 64; ++d) a += bq[h * 64 + d] * We[ce * 256 + h * 64 + d];
    val = a;
  } else {
    val = bsk[col - 1024];
  }
  bb[col] = val;
}

// Wpost for the deferred West GEMM: Wt2[col][k], k = h*64+ce, value We[ce][h*64+col]
__global__ void prep_wpost(const float* __restrict__ We, float* __restrict__ Wt2) {
  int i = blockIdx.x * blockDim.x + threadIdx.x;
  if (i >= 64 * 256) return;
  int col = i >> 8, k = i & 255;
  int h = k >> 6, ce = k & 63;
  Wt2[i] = We[ce * 256 + h * 64 + col];
}

// ---------------- fp32 node GEMM: out = X[N,fin] @ Wt^T + b ----------------
__global__ __launch_bounds__(256) void node_gemm_f32(
    const float* __restrict__ X, const float* __restrict__ Wt, const float* __restrict__ bb,
    float* __restrict__ qq_tab, float* __restrict__ kv_tab,
    float* __restrict__ skip_tab, int n, int fin) {
  __shared__ __align__(16) float Xs[128][68];
  __shared__ __align__(16) float Ws[64][68];
  int tid = threadIdx.x;
  int tx = tid & 15, ty = tid >> 4;
  int m0 = blockIdx.x * 128, c0 = blockIdx.y * 64;
  float acc[8][4];
  #pragma unroll
  for (int i = 0; i < 8; ++i)
    #pragma unroll
    for (int j = 0; j < 4; ++j) acc[i][j] = 0.f;

  for (int k0 = 0; k0 < fin; k0 += 64) {
    #pragma unroll
    for (int p = 0; p < 8; ++p) {
      int r = ty + 16 * p;
      float4 xv = make_float4(0.f, 0.f, 0.f, 0.f);
      if (m0 + r < n) xv = *(const float4*)&X[(size_t)(m0 + r) * fin + k0 + tx * 4];
      *(float4*)&Xs[r][tx * 4] = xv;
    }
    #pragma unroll
    for (int p = 0; p < 4; ++p) {
      int r = ty + 16 * p;
      float4 wv = *(const float4*)&Wt[(size_t)(c0 + r) * fin + k0 + tx * 4];
      *(float4*)&Ws[r][tx * 4] = wv;
    }
    __syncthreads();
    #pragma unroll 4
    for (int kk = 0; kk < 64; kk += 4) {
      float4 a[8], b[4];
      #pragma unroll
      for (int i = 0; i < 8; ++i) a[i] = *(const float4*)&Xs[ty + 16 * i][kk];
      #pragma unroll
      for (int j = 0; j < 4; ++j) b[j] = *(const float4*)&Ws[tx + 16 * j][kk];
      #pragma unroll
      for (int i = 0; i < 8; ++i)
        #pragma unroll
        for (int j = 0; j < 4; ++j) {
          acc[i][j] = fmaf(a[i].x, b[j].x, acc[i][j]);
          acc[i][j] = fmaf(a[i].y, b[j].y, acc[i][j]);
          acc[i][j] = fmaf(a[i].z, b[j].z, acc[i][j]);
          acc[i][j] = fmaf(a[i].w, b[j].w, acc[i][j]);
        }
    }
    __syncthreads();
  }
  #pragma unroll
  for (int j = 0; j < 4; ++j) {
    int col = c0 + tx + 16 * j;
    float bias = bb[col];
    #pragma unroll
    for (int i = 0; i < 8; ++i) {
      int row = m0 + ty + 16 * i;
      if (row >= n) continue;
      float val = acc[i][j] + bias;
      if (col < 256)        qq_tab[(size_t)row * 512 + col] = val;          // q
      else if (col < 768)   kv_tab[(size_t)row * 512 + col - 256] = val;    // k | v
      else if (col < 1024)  qq_tab[(size_t)row * 512 + col - 768 + 256] = val; // qt
      else                  skip_tab[(size_t)row * 64 + col - 1024] = val;
    }
  }
}

// ---------------- post GEMM: post[n][64] = awn[n][256] @ Wt2[64][256]^T ----------------
__global__ __launch_bounds__(256) void post_gemm(
    const float* __restrict__ A, const float* __restrict__ B, float* __restrict__ C, int n) {
  __shared__ __align__(16) float Xs[128][68];
  __shared__ __align__(16) float Ws[64][68];
  int tid = threadIdx.x;
  int tx = tid & 15, ty = tid >> 4;
  int m0 = blockIdx.x * 128;
  float acc[8][4];
  #pragma unroll
  for (int i = 0; i < 8; ++i)
    #pragma unroll
    for (int j = 0; j < 4; ++j) acc[i][j] = 0.f;

  for (int k0 = 0; k0 < 256; k0 += 64) {
    #pragma unroll
    for (int p = 0; p < 8; ++p) {
      int r = ty + 16 * p;
      float4 xv = make_float4(0.f, 0.f, 0.f, 0.f);
      if (m0 + r < n) xv = *(const float4*)&A[(size_t)(m0 + r) * 256 + k0 + tx * 4];
      *(float4*)&Xs[r][tx * 4] = xv;
    }
    #pragma unroll
    for (int p = 0; p < 4; ++p) {
      int r = ty + 16 * p;
      float4 wv = *(const float4*)&B[(size_t)r * 256 + k0 + tx * 4];
      *(float4*)&Ws[r][tx * 4] = wv;
    }
    __syncthreads();
    #pragma unroll 4
    for (int kk = 0; kk < 64; kk += 4) {
      float4 a[8], b[4];
      #pragma unroll
      for (int i = 0; i < 8; ++i) a[i] = *(const float4*)&Xs[ty + 16 * i][kk];
      #pragma unroll
      for (int j = 0; j < 4; ++j) b[j] = *(const float4*)&Ws[tx + 16 * j][kk];
      #pragma unroll
      for (int i = 0; i < 8; ++i)
        #pragma unroll
        for (int j = 0; j < 4; ++j) {
          acc[i][j] = fmaf(a[i].x, b[j].x, acc[i][j]);
          acc[i][j] = fmaf(a[i].y, b[j].y, acc[i][j]);
          acc[i][j] = fmaf(a[i].z, b[j].z, acc[i][j]);
          acc[i][j] = fmaf(a[i].w, b[j].w, acc[i][j]);
        }
    }
    __syncthreads();
  }
  #pragma unroll
  for (int j = 0; j < 4; ++j) {
    int col = tx + 16 * j;
    #pragma unroll
    for (int i = 0; i < 8; ++i) {
      int row = m0 + ty + 16 * i;
      if (row >= n) continue;
      C[(size_t)row * 64 + col] = acc[i][j];
    }
  }
}

// ---------------- attention v6: 1 node/wave, no West matvec ----------------
// lane = h*16 + c16: head h = lane>>4, channel quad c16 = lane&15 (channels c16*4..+3).
// K/V loads: 64 lanes x 16B contiguous (16 lines, 1 instr). E: 4 lines.
__global__ __launch_bounds__(256) void attn_kernel_v6(
    const int* __restrict__ row_ptr, const int* __restrict__ src_sorted,
    const int* __restrict__ eid_sorted, const float* __restrict__ ea,
    const float* __restrict__ ea_csr, int use_csr,
    const float* __restrict__ qq_tab, const float* __restrict__ kv_tab,
    float* __restrict__ avs_tab, float* __restrict__ awn_tab, int n) {
  int tid = threadIdx.x;
  int wave = tid >> 6, lane = tid & 63;
  int c16 = lane & 15;
  const float4* qq4 = (const float4*)qq_tab;
  const float4* kv4 = (const float4*)kv_tab;
  const float4* ec4 = (const float4*)ea_csr;
  const float4* e4p = (const float4*)ea;

  int node = blockIdx.x * 4 + wave;
  if (node >= n) return;
  int beg = row_ptr[node];
  int deg = row_ptr[node + 1] - beg;

  float4 q4 = qq4[(size_t)node * 128 + lane];
  float4 t4 = qq4[(size_t)node * 128 + 64 + lane];

  float m = -INFINITY, s = 0.f;
  float4 av = make_float4(0.f, 0.f, 0.f, 0.f);
  float4 aw = make_float4(0.f, 0.f, 0.f, 0.f);

#define LDE(j_, K_, V_, E_)                                   \
  {                                                           \
    int jc = (j_); int jm = beg + deg - 1;                    \
    if (jc > jm) jc = jm;                                     \
    int s_ = src_sorted[jc];                                  \
    const float4* kr = kv4 + (size_t)s_ * 128;                \
    K_ = kr[lane]; V_ = kr[64 + lane];                        \
    if (use_csr) E_ = ec4[(size_t)jc * 16 + c16];             \
    else { int e_ = eid_sorted[jc];                           \
           E_ = e4p[(size_t)e_ * 16 + c16]; }                 \
  }

#define PROC(K_, V_, E_)                                      \
  {                                                           \
    float p = q4.x * K_.x + q4.y * K_.y + q4.z * K_.z + q4.w * K_.w \
            + t4.x * E_.x + t4.y * E_.y + t4.z * E_.z + t4.w * E_.w; \
    p += __shfl_xor(p, 1);                                    \
    p += __shfl_xor(p, 2);                                    \
    p += __shfl_xor(p, 4);                                    \
    p += __shfl_xor(p, 8);                                    \
    p *= 0.125f;                                              \
    float d_ = p - m;                                         \
    float e_ = __expf(-fabsf(d_));                            \
    float sc = d_ > 0.f ? e_ : 1.f;                           \
    float pp = d_ > 0.f ? 1.f : e_;                           \
    m = fmaxf(m, p);                                          \
    s = s * sc + pp;                                          \
    av.x = av.x * sc + pp * V_.x; av.y = av.y * sc + pp * V_.y; \
    av.z = av.z * sc + pp * V_.z; av.w = av.w * sc + pp * V_.w; \
    aw.x = aw.x * sc + pp * E_.x; aw.y = aw.y * sc + pp * E_.y; \
    aw.z = aw.z * sc + pp * E_.z; aw.w = aw.w * sc + pp * E_.w; \
  }

  if (deg > 0) {
    float4 KA, VA, EA, KB, VB, EB;
    LDE(beg + 0, KA, VA, EA);
    LDE(beg + 1, KB, VB, EB);
    int t = 0;
    for (; t + 1 < deg; t += 2) {
      {
        float4 nK, nV, nE;
        LDE(beg + t + 2, nK, nV, nE);
        PROC(KA, VA, EA);
        KA = nK; VA = nV; EA = nE;
      }
      {
        float4 nK, nV, nE;
        LDE(beg + t + 3, nK, nV, nE);
        PROC(KB, VB, EB);
        KB = nK; VB = nV; EB = nE;
      }
    }
    if (t < deg) PROC(KA, VA, EA);
  }

  float inv = s > 0.f ? 1.f / s : 0.f;
  float4 awn = make_float4(aw.x * inv, aw.y * inv, aw.z * inv, aw.w * inv);
  float4 avn = make_float4(av.x * inv, av.y * inv, av.z * inv, av.w * inv);

  // awn: all 64 lanes write their (h, ce-quad) -> [node][h*64 + c16*4] = 1KB contiguous
  ((float4*)awn_tab)[(size_t)node * 64 + lane] = awn;

  // head-sum of avn across h (lane bits 4,5)
  avn.x += __shfl_xor(avn.x, 16); avn.y += __shfl_xor(avn.y, 16);
  avn.z += __shfl_xor(avn.z, 16); avn.w += __shfl_xor(avn.w, 16);
  avn.x += __shfl_xor(avn.x, 32); avn.y += __shfl_xor(avn.y, 32);
  avn.z += __shfl_xor(avn.z, 32); avn.w += __shfl_xor(avn.w, 32);
  if (lane < 16)
    ((float4*)avs_tab)[(size_t)node * 16 + c16] = avn;
}

// ---------------- finish: head-mean + skip + GN + GELU ----------------
__global__ void finish_kernel(const float* __restrict__ avs, const float* __restrict__ post,
                              const float* __restrict__ skip, const float* __restrict__ gnw,
                              const float* __restrict__ gnb, float* __restrict__ out, int n) {
  int g = blockIdx.x * blockDim.x + threadIdx.x;
  if (g >= n * 16) return;
  int node = g >> 4, grp = g & 15;
  float4 a = ((const float4*)avs)[(size_t)node * 16 + grp];
  float4 p = ((const float4*)post)[(size_t)node * 16 + grp];
  float4 sk = ((const float4*)skip)[(size_t)node * 16 + grp];
  float4 gw = ((const float4*)gnw)[grp];
  float4 gb = ((const float4*)gnb)[grp];
  float v0 = 0.25f * (a.x + p.x) + sk.x;
  float v1 = 0.25f * (a.y + p.y) + sk.y;
  float v2 = 0.25f * (a.z + p.z) + sk.z;
  float v3 = 0.25f * (a.w + p.w) + sk.w;
  float mu = ((v0 + v1) + (v2 + v3)) * 0.25f;
  float d0 = v0 - mu, d1 = v1 - mu, d2 = v2 - mu, d3 = v3 - mu;
  float var = ((d0 * d0 + d1 * d1) + (d2 * d2 + d3 * d3)) * 0.25f;
  float r = rsqrtf(var + 1e-5f);
  float y0 = d0 * r * gw.x + gb.x;
  float y1 = d1 * r * gw.y + gb.y;
  float y2 = d2 * r * gw.z + gb.z;
  float y3 = d3 * r * gw.w + gb.w;
  #define GELU(y) (0.5f * (y) * (1.0f + erff((y) * 0.70710678118654752f)))
  float4 o;
  o.x = GELU(y0); o.y = GELU(y1); o.z = GELU(y2); o.w = GELU(y3);
  ((float4*)out)[(size_t)node * 16 + grp] = o;
}

// ---------------- host ----------------
extern "C" void kernel_launch(void* const* d_in, const int* in_sizes, int n_in,
                              void* d_out, int out_size, void* d_ws, size_t ws_size,
                              hipStream_t stream) {
  (void)in_sizes; (void)n_in;
  const float* x = (const float*)d_in[0];
  const void* ei = d_in[1];
  const float* ea = (const float*)d_in[2];
  const float *Wq[3], *bq[3], *Wk[3], *bk[3], *Wv[3], *bv[3], *We[3], *Wsk[3], *bsk[3];
  for (int L = 0; L < 3; ++L) {
    int b = 3 + 9 * L;
    Wq[L] = (const float*)d_in[b + 0]; bq[L] = (const float*)d_in[b + 1];
    Wk[L] = (const float*)d_in[b + 2]; bk[L] = (const float*)d_in[b + 3];
    Wv[L] = (const float*)d_in[b + 4]; bv[L] = (const float*)d_in[b + 5];
    We[L] = (const float*)d_in[b + 6]; Wsk[L] = (const float*)d_in[b + 7];
    bsk[L] = (const float*)d_in[b + 8];
  }
  const float* gnw = (const float*)d_in[30];
  const float* gnb = (const float*)d_in[31];

  char* p = (char*)d_ws;
  auto alloc = [&](size_t bytes) -> void* {
    void* r = (void*)p;
    p += (bytes + 255) & ~(size_t)255;
    return r;
  };
  float* qq_tab = (float*)alloc((size_t)NN * 512 * 4);
  float* kv_tab = (float*)alloc((size_t)NN * 512 * 4);
  float* skip_tab = (float*)alloc((size_t)NN * 64 * 4);
  float* h_buf = (float*)alloc((size_t)NN * 64 * 4);
  float* avs_tab = (float*)alloc((size_t)NN * 64 * 4);
  float* awn_tab = (float*)alloc((size_t)NN * 256 * 4);
  float* post_tab = (float*)alloc((size_t)NN * 64 * 4);
  int* row_ptr = (int*)alloc((size_t)(NN + 1) * 4);
  int* deg = (int*)alloc((size_t)NN * 4);
  int* cursor = (int*)alloc((size_t)NN * 4);
  int* csum = (int*)alloc(1024 * 4);
  int* src_sorted = (int*)alloc((size_t)NE * 4);
  int* eid_sorted = (int*)alloc((size_t)NE * 4);
  int* src32 = (int*)alloc((size_t)NE * 4);
  int* dst32 = (int*)alloc((size_t)NE * 4);
  int* flag = (int*)alloc(256);
  float* Wt[3]; float* bb[3]; float* Wt2[3];
  Wt[0] = (float*)alloc((size_t)NCOLS * 128 * 4);
  Wt[1] = (float*)alloc((size_t)NCOLS * 64 * 4);
  Wt[2] = (float*)alloc((size_t)NCOLS * 64 * 4);
  for (int L = 0; L < 3; ++L) bb[L] = (float*)alloc((size_t)NCOLS * 4);
  for (int L = 0; L < 3; ++L) Wt2[L] = (float*)alloc((size_t)64 * 256 * 4);

  // Workspace overflow guard (all-zero output == error 1.65625 signature).
  if ((size_t)(p - (char*)d_ws) > ws_size) {
    hipMemsetAsync(d_out, 0, (size_t)out_size * 4, stream);
    return;
  }

  // Optional ea_csr buffer (205 MB).
  float* ea_csr = nullptr;
  int use_csr = 0;
  {
    size_t need = (size_t)(p - (char*)d_ws) + (size_t)NE * 64 * 4 + 256;
    if (need <= ws_size) {
      ea_csr = (float*)alloc((size_t)NE * 64 * 4);
      use_csr = 1;
    }
  }

  hipMemsetAsync(deg, 0, (size_t)NN * 4, stream);
  hipMemsetAsync(cursor, 0, (size_t)NN * 4, stream);
  hipMemsetAsync(flag, 0, 4, stream);

  detect_i64<<<8, 256, 0, stream>>>((const int*)ei, flag);
  extract_edges<<<2048, 256, 0, stream>>>(ei, flag, src32, dst32, NE);

  hist_kernel<<<2048, 256, 0, stream>>>(dst32, deg, NE);
  int nchunks = (NN + SCHUNK - 1) / SCHUNK;
  scanA<<<nchunks, SCHUNK, 0, stream>>>(deg, row_ptr, csum, NN);
  scanB<<<1, 64, 0, stream>>>(csum, nchunks);
  scanC<<<nchunks, SCHUNK, 0, stream>>>(row_ptr, csum, NN);
  scatter_kernel<<<2048, 256, 0, stream>>>(src32, dst32, row_ptr, cursor, src_sorted, eid_sorted, NE);
  sort_lists<<<(NN + 255) / 256, 256, 0, stream>>>(row_ptr, src_sorted, eid_sorted, NN);
  if (use_csr)
    ea_gather<<<2048, 256, 0, stream>>>(eid_sorted, ea, ea_csr, NE);

  for (int L = 0; L < 3; ++L) {
    int fin = (L == 0) ? 128 : 64;
    prep_wt<<<(NCOLS * fin + 255) / 256, 256, 0, stream>>>(Wq[L], Wk[L], Wv[L], We[L], Wsk[L], Wt[L], fin);
    prep_bias<<<(NCOLS + 255) / 256, 256, 0, stream>>>(bq[L], bk[L], bv[L], We[L], bsk[L], bb[L]);
    prep_wpost<<<64, 256, 0, stream>>>(We[L], Wt2[L]);
  }

  const float* hin = x;
  int nblk = (NN + 3) / 4;
  for (int L = 0; L < 3; ++L) {
    int fin = (L == 0) ? 128 : 64;
    dim3 g((NN + 127) / 128, 17);
    node_gemm_f32<<<g, 256, 0, stream>>>(hin, Wt[L], bb[L], qq_tab, kv_tab, skip_tab, NN, fin);
    attn_kernel_v6<<<nblk, 256, 0, stream>>>(
        row_ptr, src_sorted, eid_sorted, ea, ea_csr, use_csr,
        qq_tab, kv_tab, avs_tab, awn_tab, NN);
    post_gemm<<<(NN + 127) / 128, 256, 0, stream>>>(awn_tab, Wt2[L], post_tab, NN);
    finish_kernel<<<(NN * 16 + 255) / 256, 256, 0, stream>>>(
        avs_tab, post_tab, skip_tab, gnw, gnb,
        (L == 2) ? (float*)d_out : h_buf, NN);
    hin = h_buf;
  }
}

// Round 11
// 1535.970 us; speedup vs baseline: 1.2278x; 1.1464x over previous
//
#include <hip/hip_runtime.h>
#include <math.h>

#define NN 50000
#define NE 800000
#define NCOLS 1088   // 256 q | 256 k | 256 v | 256 qt | 64 skip   (cols are h*64+d order)

typedef long long i64;
typedef unsigned short u16;
typedef short bf16x8 __attribute__((ext_vector_type(8)));
typedef unsigned short u16x8 __attribute__((ext_vector_type(8)));
typedef float f32x4 __attribute__((ext_vector_type(4)));

static __device__ __forceinline__ float bf2f(u16 u) {
  union { float f; unsigned b; } x; x.b = ((unsigned)u) << 16; return x.f;
}
static __device__ __forceinline__ u16 f2bf(float f) {
  union { float f; unsigned b; } x; x.f = f;
  unsigned r = x.b + 0x7FFFu + ((x.b >> 16) & 1u);
  return (u16)(r >> 16);
}

// ---------------- edge-index dtype probe + extraction ----------------
__global__ void detect_i64(const int* __restrict__ ei32, int* __restrict__ flag) {
  int i = blockIdx.x * blockDim.x + threadIdx.x;
  if (i < 2048) {
    if (ei32[2 * i + 1] != 0) atomicOr(flag, 1);  // 1 -> data is int32
  }
}

__global__ void extract_edges(const void* __restrict__ ei, const int* __restrict__ flag,
                              int* __restrict__ src32, int* __restrict__ dst32, int ne) {
  int is32 = *flag;
  int i = blockIdx.x * blockDim.x + threadIdx.x;
  int st = gridDim.x * blockDim.x;
  if (is32) {
    const int* p = (const int*)ei;
    for (; i < ne; i += st) { src32[i] = p[i]; dst32[i] = p[ne + i]; }
  } else {
    const i64* p = (const i64*)ei;
    for (; i < ne; i += st) { src32[i] = (int)p[i]; dst32[i] = (int)p[ne + i]; }
  }
}

// ---------------- CSR build ----------------
__global__ void hist_kernel(const int* __restrict__ dst, int* __restrict__ deg, int ne) {
  int i = blockIdx.x * blockDim.x + threadIdx.x;
  int st = gridDim.x * blockDim.x;
  for (; i < ne; i += st) atomicAdd(&deg[dst[i]], 1);
}

#define SCHUNK 1024
__global__ void scanA(const int* __restrict__ deg, int* __restrict__ row_ptr,
                      int* __restrict__ csum, int n) {
  __shared__ int buf[SCHUNK];
  int c = blockIdx.x, t = threadIdx.x;
  int idx = c * SCHUNK + t;
  int v = (idx < n) ? deg[idx] : 0;
  buf[t] = v;
  __syncthreads();
  for (int off = 1; off < SCHUNK; off <<= 1) {
    int x = (t >= off) ? buf[t - off] : 0;
    __syncthreads();
    buf[t] += x;
    __syncthreads();
  }
  if (idx < n) row_ptr[idx + 1] = buf[t];
  if (t == SCHUNK - 1) csum[c] = buf[t];
}

__global__ void scanB(int* __restrict__ csum, int nchunks) {
  if (threadIdx.x == 0 && blockIdx.x == 0) {
    int run = 0;
    for (int c = 0; c < nchunks; ++c) { int v = csum[c]; csum[c] = run; run += v; }
  }
}

__global__ void scanC(int* __restrict__ row_ptr, const int* __restrict__ csum, int n) {
  int c = blockIdx.x, t = threadIdx.x;
  int idx = c * SCHUNK + t;
  if (idx < n) row_ptr[idx + 1] += csum[c];
  if (idx == 0) row_ptr[0] = 0;
}

__global__ void scatter_kernel(const int* __restrict__ src, const int* __restrict__ dst,
                               const int* __restrict__ row_ptr, int* __restrict__ cursor,
                               int* __restrict__ src_sorted, int* __restrict__ eid_sorted, int ne) {
  int i = blockIdx.x * blockDim.x + threadIdx.x;
  int st = gridDim.x * blockDim.x;
  for (; i < ne; i += st) {
    int d = dst[i];
    int pos = row_ptr[d] + atomicAdd(&cursor[d], 1);
    src_sorted[pos] = src[i];
    eid_sorted[pos] = i;
  }
}

// Deterministic order: sort each node's edge list by eid.
__global__ void sort_lists(const int* __restrict__ row_ptr, int* __restrict__ src_sorted,
                           int* __restrict__ eid_sorted, int n) {
  int node = blockIdx.x * blockDim.x + threadIdx.x;
  if (node >= n) return;
  int beg = row_ptr[node], end = row_ptr[node + 1];
  for (int a = beg + 1; a < end; ++a) {
    int e = eid_sorted[a], s = src_sorted[a];
    int b = a - 1;
    while (b >= beg && eid_sorted[b] > e) {
      eid_sorted[b + 1] = eid_sorted[b];
      src_sorted[b + 1] = src_sorted[b];
      --b;
    }
    eid_sorted[b + 1] = e; src_sorted[b + 1] = s;
  }
}

// ---------------- ea pre-gather into CSR order ----------
__global__ void ea_gather(const int* __restrict__ eid_sorted, const float* __restrict__ ea,
                          float* __restrict__ ea_csr, int ne) {
  long total = (long)ne * 16;
  long st = (long)gridDim.x * blockDim.x;
  for (long i = (long)blockIdx.x * blockDim.x + threadIdx.x; i < total; i += st) {
    int j = (int)(i >> 4);
    int c = (int)(i & 15);
    int e = eid_sorted[j];
    ((float4*)ea_csr)[i] = ((const float4*)ea)[(size_t)e * 16 + c];
  }
}

// ---------------- split fp32 -> bf16 hi + bf16 lo ----------------
__global__ void cvt_split(const float* __restrict__ in, u16* __restrict__ hi,
                          u16* __restrict__ lo, int nElem) {
  int i = blockIdx.x * blockDim.x + threadIdx.x;
  int st = gridDim.x * blockDim.x;
  for (; i < nElem; i += st) {
    float v = in[i];
    u16 h = f2bf(v);
    hi[i] = h;
    lo[i] = f2bf(v - bf2f(h));
  }
}

// ---------------- weight prep (fp32, head-major cols) ----------------
__global__ void prep_wt(const float* __restrict__ Wq, const float* __restrict__ Wk,
                        const float* __restrict__ Wv, const float* __restrict__ We,
                        const float* __restrict__ Wsk, float* __restrict__ Wt, int fin) {
  int i = blockIdx.x * blockDim.x + threadIdx.x;
  if (i >= NCOLS * fin) return;
  int col = i / fin, k = i % fin;
  float val;
  if (col < 768) {
    const float* W = (col < 256) ? Wq : (col < 512) ? Wk : Wv;
    val = W[k * 256 + (col & 255)];
  } else if (col < 1024) {
    int idx = col - 768; int h = idx >> 6, ce = idx & 63;
    float a = 0.f;
    for (int d = 0; d < 64; ++d) a += Wq[k * 256 + h * 64 + d] * We[ce * 256 + h * 64 + d];
    val = a;
  } else {
    val = Wsk[k * 64 + (col - 1024)];
  }
  Wt[(size_t)col * fin + k] = val;
}

__global__ void prep_bias(const float* __restrict__ bq, const float* __restrict__ bk,
                          const float* __restrict__ bv, const float* __restrict__ We,
                          const float* __restrict__ bsk, float* __restrict__ bb) {
  int col = blockIdx.x * blockDim.x + threadIdx.x;
  if (col >= NCOLS) return;
  float val;
  if (col < 768) {
    const float* b = (col < 256) ? bq : (col < 512) ? bk : bv;
    val = b[col & 255];
  } else if (col < 1024) {
    int idx = col - 768; int h = idx >> 6, ce = idx & 63;
    float a = 0.f;
    for (int d = 0; d < 64; ++d) a += bq[h * 64 + d] * We[ce * 256 + h * 64 + d];
    val = a;
  } else {
    val = bsk[col - 1024];
  }
  bb[col] = val;
}

// Wpost for the deferred West GEMM: Wt2[col][k], k = h*64+ce, value We[ce][h*64+col]
__global__ void prep_wpost(const float* __restrict__ We, float* __restrict__ Wt2) {
  int i = blockIdx.x * blockDim.x + threadIdx.x;
  if (i >= 64 * 256) return;
  int col = i >> 8, k = i & 255;
  int h = k >> 6, ce = k & 63;
  Wt2[i] = We[ce * 256 + h * 64 + col];
}

// ---------------- split-bf16 MFMA node GEMM: out = X @ Wt^T + b ----------------
// C ~= Xhi@Whi + Xhi@Wlo + Xlo@Whi (3 MFMAs; lo*lo dropped ~2^-18 rel).
// 64x64 tile, 4 waves; wave w rows w*16..+15, 4 col-frags of 16.
__global__ __launch_bounds__(256) void node_gemm_mfma(
    const u16* __restrict__ Xhi, const u16* __restrict__ Xlo,
    const u16* __restrict__ Whi, const u16* __restrict__ Wlo,
    const float* __restrict__ bb,
    float* __restrict__ qq_tab, float* __restrict__ kv_tab,
    float* __restrict__ skip_tab, int n, int fin) {
  __shared__ __align__(16) u16 Ah[64][72];
  __shared__ __align__(16) u16 Al[64][72];
  __shared__ __align__(16) u16 Bh[64][72];
  __shared__ __align__(16) u16 Bl[64][72];
  int tid = threadIdx.x, wave = tid >> 6, lane = tid & 63;
  int c0 = blockIdx.x * 64, m0 = blockIdx.y * 64;
  f32x4 acc[4];
  #pragma unroll
  for (int i = 0; i < 4; ++i) acc[i] = (f32x4){0.f, 0.f, 0.f, 0.f};

  int lr = tid >> 2, sg = (tid & 3) * 16;
  for (int k0 = 0; k0 < fin; k0 += 64) {
    u16x8 z = {0, 0, 0, 0, 0, 0, 0, 0};
    u16x8 a0 = z, a1 = z, l0 = z, l1 = z;
    if (m0 + lr < n) {
      const u16* ph = &Xhi[(size_t)(m0 + lr) * fin + k0 + sg];
      a0 = *(const u16x8*)ph; a1 = *(const u16x8*)(ph + 8);
      const u16* pl = &Xlo[(size_t)(m0 + lr) * fin + k0 + sg];
      l0 = *(const u16x8*)pl; l1 = *(const u16x8*)(pl + 8);
    }
    *(u16x8*)&Ah[lr][sg] = a0; *(u16x8*)&Ah[lr][sg + 8] = a1;
    *(u16x8*)&Al[lr][sg] = l0; *(u16x8*)&Al[lr][sg + 8] = l1;
    {
      const u16* ph = &Whi[(size_t)(c0 + lr) * fin + k0 + sg];
      *(u16x8*)&Bh[lr][sg] = *(const u16x8*)ph;
      *(u16x8*)&Bh[lr][sg + 8] = *(const u16x8*)(ph + 8);
      const u16* pl = &Wlo[(size_t)(c0 + lr) * fin + k0 + sg];
      *(u16x8*)&Bl[lr][sg] = *(const u16x8*)pl;
      *(u16x8*)&Bl[lr][sg + 8] = *(const u16x8*)(pl + 8);
    }
    __syncthreads();
    int arow = wave * 16 + (lane & 15);
    int kb = (lane >> 4) * 8;
    #pragma unroll
    for (int ks = 0; ks < 2; ++ks) {
      bf16x8 ah = *(const bf16x8*)&Ah[arow][ks * 32 + kb];
      bf16x8 al_ = *(const bf16x8*)&Al[arow][ks * 32 + kb];
      #pragma unroll
      for (int nf = 0; nf < 4; ++nf) {
        bf16x8 bh = *(const bf16x8*)&Bh[nf * 16 + (lane & 15)][ks * 32 + kb];
        bf16x8 bl = *(const bf16x8*)&Bl[nf * 16 + (lane & 15)][ks * 32 + kb];
        acc[nf] = __builtin_amdgcn_mfma_f32_16x16x32_bf16(ah, bh, acc[nf], 0, 0, 0);
        acc[nf] = __builtin_amdgcn_mfma_f32_16x16x32_bf16(ah, bl, acc[nf], 0, 0, 0);
        acc[nf] = __builtin_amdgcn_mfma_f32_16x16x32_bf16(al_, bh, acc[nf], 0, 0, 0);
      }
    }
    __syncthreads();
  }
  int rbase = m0 + wave * 16 + (lane >> 4) * 4;
  int cl = lane & 15;
  #pragma unroll
  for (int nf = 0; nf < 4; ++nf) {
    int col = c0 + nf * 16 + cl;
    float bias = bb[col];
    #pragma unroll
    for (int r = 0; r < 4; ++r) {
      int row = rbase + r;
      if (row >= n) continue;
      float val = acc[nf][r] + bias;
      if (col < 256)        qq_tab[(size_t)row * 512 + col] = val;           // q
      else if (col < 768)   kv_tab[(size_t)row * 512 + col - 256] = val;     // k | v
      else if (col < 1024)  qq_tab[(size_t)row * 512 + col - 512] = val;     // qt
      else                  skip_tab[(size_t)row * 64 + col - 1024] = val;
    }
  }
}

// ---------------- attention v6: 1 node/wave, no West matvec ----------------
__global__ __launch_bounds__(256) void attn_kernel_v6(
    const int* __restrict__ row_ptr, const int* __restrict__ src_sorted,
    const int* __restrict__ eid_sorted, const float* __restrict__ ea,
    const float* __restrict__ ea_csr, int use_csr,
    const float* __restrict__ qq_tab, const float* __restrict__ kv_tab,
    float* __restrict__ avs_tab, float* __restrict__ awn_tab, int n) {
  int tid = threadIdx.x;
  int wave = tid >> 6, lane = tid & 63;
  int c16 = lane & 15;
  const float4* qq4 = (const float4*)qq_tab;
  const float4* kv4 = (const float4*)kv_tab;
  const float4* ec4 = (const float4*)ea_csr;
  const float4* e4p = (const float4*)ea;

  int node = blockIdx.x * 4 + wave;
  if (node >= n) return;
  int beg = row_ptr[node];
  int deg = row_ptr[node + 1] - beg;

  float4 q4 = qq4[(size_t)node * 128 + lane];
  float4 t4 = qq4[(size_t)node * 128 + 64 + lane];

  float m = -INFINITY, s = 0.f;
  float4 av = make_float4(0.f, 0.f, 0.f, 0.f);
  float4 aw = make_float4(0.f, 0.f, 0.f, 0.f);

#define LDE(j_, K_, V_, E_)                                   \
  {                                                           \
    int jc = (j_); int jm = beg + deg - 1;                    \
    if (jc > jm) jc = jm;                                     \
    int s_ = src_sorted[jc];                                  \
    const float4* kr = kv4 + (size_t)s_ * 128;                \
    K_ = kr[lane]; V_ = kr[64 + lane];                        \
    if (use_csr) E_ = ec4[(size_t)jc * 16 + c16];             \
    else { int e_ = eid_sorted[jc];                           \
           E_ = e4p[(size_t)e_ * 16 + c16]; }                 \
  }

#define PROC(K_, V_, E_)                                      \
  {                                                           \
    float p = q4.x * K_.x + q4.y * K_.y + q4.z * K_.z + q4.w * K_.w \
            + t4.x * E_.x + t4.y * E_.y + t4.z * E_.z + t4.w * E_.w; \
    p += __shfl_xor(p, 1);                                    \
    p += __shfl_xor(p, 2);                                    \
    p += __shfl_xor(p, 4);                                    \
    p += __shfl_xor(p, 8);                                    \
    p *= 0.125f;                                              \
    float d_ = p - m;                                         \
    float e_ = __expf(-fabsf(d_));                            \
    float sc = d_ > 0.f ? e_ : 1.f;                           \
    float pp = d_ > 0.f ? 1.f : e_;                           \
    m = fmaxf(m, p);                                          \
    s = s * sc + pp;                                          \
    av.x = av.x * sc + pp * V_.x; av.y = av.y * sc + pp * V_.y; \
    av.z = av.z * sc + pp * V_.z; av.w = av.w * sc + pp * V_.w; \
    aw.x = aw.x * sc + pp * E_.x; aw.y = aw.y * sc + pp * E_.y; \
    aw.z = aw.z * sc + pp * E_.z; aw.w = aw.w * sc + pp * E_.w; \
  }

  if (deg > 0) {
    float4 KA, VA, EA, KB, VB, EB;
    LDE(beg + 0, KA, VA, EA);
    LDE(beg + 1, KB, VB, EB);
    int t = 0;
    for (; t + 1 < deg; t += 2) {
      {
        float4 nK, nV, nE;
        LDE(beg + t + 2, nK, nV, nE);
        PROC(KA, VA, EA);
        KA = nK; VA = nV; EA = nE;
      }
      {
        float4 nK, nV, nE;
        LDE(beg + t + 3, nK, nV, nE);
        PROC(KB, VB, EB);
        KB = nK; VB = nV; EB = nE;
      }
    }
    if (t < deg) PROC(KA, VA, EA);
  }

  float inv = s > 0.f ? 1.f / s : 0.f;
  float4 awn = make_float4(aw.x * inv, aw.y * inv, aw.z * inv, aw.w * inv);
  float4 avn = make_float4(av.x * inv, av.y * inv, av.z * inv, av.w * inv);

  ((float4*)awn_tab)[(size_t)node * 64 + lane] = awn;

  avn.x += __shfl_xor(avn.x, 16); avn.y += __shfl_xor(avn.y, 16);
  avn.z += __shfl_xor(avn.z, 16); avn.w += __shfl_xor(avn.w, 16);
  avn.x += __shfl_xor(avn.x, 32); avn.y += __shfl_xor(avn.y, 32);
  avn.z += __shfl_xor(avn.z, 32); avn.w += __shfl_xor(avn.w, 32);
  if (lane < 16)
    ((float4*)avs_tab)[(size_t)node * 16 + c16] = avn;
}

// ---------------- post GEMM + fused head-mean/skip/GN/GELU (+ optional bf16 split out) ----
// post[n][64] = awn[n][256] @ Wt2[64][256]^T, then per 4-channel group GN.
__global__ __launch_bounds__(256) void post_gn(
    const float* __restrict__ A, const float* __restrict__ B,
    const float* __restrict__ avs, const float* __restrict__ skip,
    const float* __restrict__ gnw, const float* __restrict__ gnb,
    float* __restrict__ out_f32, u16* __restrict__ out_hi, u16* __restrict__ out_lo, int n) {
  __shared__ __align__(16) float Xs[128][68];
  __shared__ __align__(16) float Ws[64][68];
  int tid = threadIdx.x;
  int tx = tid & 15, ty = tid >> 4;
  int m0 = blockIdx.x * 128;
  float acc[8][4];
  #pragma unroll
  for (int i = 0; i < 8; ++i)
    #pragma unroll
    for (int j = 0; j < 4; ++j) acc[i][j] = 0.f;

  for (int k0 = 0; k0 < 256; k0 += 64) {
    #pragma unroll
    for (int p = 0; p < 8; ++p) {
      int r = ty + 16 * p;
      float4 xv = make_float4(0.f, 0.f, 0.f, 0.f);
      if (m0 + r < n) xv = *(const float4*)&A[(size_t)(m0 + r) * 256 + k0 + tx * 4];
      *(float4*)&Xs[r][tx * 4] = xv;
    }
    #pragma unroll
    for (int p = 0; p < 4; ++p) {
      int r = ty + 16 * p;
      float4 wv = *(const float4*)&B[(size_t)r * 256 + k0 + tx * 4];
      *(float4*)&Ws[r][tx * 4] = wv;
    }
    __syncthreads();
    #pragma unroll 4
    for (int kk = 0; kk < 64; kk += 4) {
      float4 a[8], b[4];
      #pragma unroll
      for (int i = 0; i < 8; ++i) a[i] = *(const float4*)&Xs[ty + 16 * i][kk];
      #pragma unroll
      for (int j = 0; j < 4; ++j) b[j] = *(const float4*)&Ws[tx + 16 * j][kk];
      #pragma unroll
      for (int i = 0; i < 8; ++i)
        #pragma unroll
        for (int j = 0; j < 4; ++j) {
          acc[i][j] = fmaf(a[i].x, b[j].x, acc[i][j]);
          acc[i][j] = fmaf(a[i].y, b[j].y, acc[i][j]);
          acc[i][j] = fmaf(a[i].z, b[j].z, acc[i][j]);
          acc[i][j] = fmaf(a[i].w, b[j].w, acc[i][j]);
        }
    }
    __syncthreads();
  }
  // stash post into LDS for row-major epilogue
  #pragma unroll
  for (int j = 0; j < 4; ++j)
    #pragma unroll
    for (int i = 0; i < 8; ++i)
      Xs[ty + 16 * i][tx + 16 * j] = acc[i][j];
  __syncthreads();

  #pragma unroll
  for (int rep = 0; rep < 8; ++rep) {
    int id = tid + 256 * rep;
    int rl = id >> 4, grp = id & 15;
    int row = m0 + rl;
    if (row >= n) continue;
    float4 a = ((const float4*)avs)[(size_t)row * 16 + grp];
    float4 sk = ((const float4*)skip)[(size_t)row * 16 + grp];
    float4 gw = ((const float4*)gnw)[grp];
    float4 gb = ((const float4*)gnb)[grp];
    float p0 = Xs[rl][grp * 4 + 0], p1 = Xs[rl][grp * 4 + 1];
    float p2 = Xs[rl][grp * 4 + 2], p3 = Xs[rl][grp * 4 + 3];
    float v0 = 0.25f * (a.x + p0) + sk.x;
    float v1 = 0.25f * (a.y + p1) + sk.y;
    float v2 = 0.25f * (a.z + p2) + sk.z;
    float v3 = 0.25f * (a.w + p3) + sk.w;
    float mu = ((v0 + v1) + (v2 + v3)) * 0.25f;
    float d0 = v0 - mu, d1 = v1 - mu, d2 = v2 - mu, d3 = v3 - mu;
    float var = ((d0 * d0 + d1 * d1) + (d2 * d2 + d3 * d3)) * 0.25f;
    float r = rsqrtf(var + 1e-5f);
    float y0 = d0 * r * gw.x + gb.x;
    float y1 = d1 * r * gw.y + gb.y;
    float y2 = d2 * r * gw.z + gb.z;
    float y3 = d3 * r * gw.w + gb.w;
    #define GELU(y) (0.5f * (y) * (1.0f + erff((y) * 0.70710678118654752f)))
    float g0 = GELU(y0), g1 = GELU(y1), g2 = GELU(y2), g3 = GELU(y3);
    if (out_f32) {
      float4 o; o.x = g0; o.y = g1; o.z = g2; o.w = g3;
      ((float4*)out_f32)[(size_t)row * 16 + grp] = o;
    } else {
      u16 h0 = f2bf(g0), h1 = f2bf(g1), h2 = f2bf(g2), h3 = f2bf(g3);
      ushort4 hv; hv.x = h0; hv.y = h1; hv.z = h2; hv.w = h3;
      *(ushort4*)&out_hi[(size_t)row * 64 + grp * 4] = hv;
      ushort4 lv;
      lv.x = f2bf(g0 - bf2f(h0)); lv.y = f2bf(g1 - bf2f(h1));
      lv.z = f2bf(g2 - bf2f(h2)); lv.w = f2bf(g3 - bf2f(h3));
      *(ushort4*)&out_lo[(size_t)row * 64 + grp * 4] = lv;
    }
  }
}

// ---------------- host ----------------
extern "C" void kernel_launch(void* const* d_in, const int* in_sizes, int n_in,
                              void* d_out, int out_size, void* d_ws, size_t ws_size,
                              hipStream_t stream) {
  (void)in_sizes; (void)n_in;
  const float* x = (const float*)d_in[0];
  const void* ei = d_in[1];
  const float* ea = (const float*)d_in[2];
  const float *Wq[3], *bq[3], *Wk[3], *bk[3], *Wv[3], *bv[3], *We[3], *Wsk[3], *bsk[3];
  for (int L = 0; L < 3; ++L) {
    int b = 3 + 9 * L;
    Wq[L] = (const float*)d_in[b + 0]; bq[L] = (const float*)d_in[b + 1];
    Wk[L] = (const float*)d_in[b + 2]; bk[L] = (const float*)d_in[b + 3];
    Wv[L] = (const float*)d_in[b + 4]; bv[L] = (const float*)d_in[b + 5];
    We[L] = (const float*)d_in[b + 6]; Wsk[L] = (const float*)d_in[b + 7];
    bsk[L] = (const float*)d_in[b + 8];
  }
  const float* gnw = (const float*)d_in[30];
  const float* gnb = (const float*)d_in[31];

  char* p = (char*)d_ws;
  auto alloc = [&](size_t bytes) -> void* {
    void* r = (void*)p;
    p += (bytes + 255) & ~(size_t)255;
    return r;
  };
  float* qq_tab = (float*)alloc((size_t)NN * 512 * 4);
  float* kv_tab = (float*)alloc((size_t)NN * 512 * 4);
  float* skip_tab = (float*)alloc((size_t)NN * 64 * 4);
  float* avs_tab = (float*)alloc((size_t)NN * 64 * 4);
  float* awn_tab = (float*)alloc((size_t)NN * 256 * 4);
  u16* xhi = (u16*)alloc((size_t)NN * 128 * 2);
  u16* xlo = (u16*)alloc((size_t)NN * 128 * 2);
  u16* hhi = (u16*)alloc((size_t)NN * 64 * 2);
  u16* hlo = (u16*)alloc((size_t)NN * 64 * 2);
  int* row_ptr = (int*)alloc((size_t)(NN + 1) * 4);
  int* deg = (int*)alloc((size_t)NN * 4);
  int* cursor = (int*)alloc((size_t)NN * 4);
  int* csum = (int*)alloc(1024 * 4);
  int* src_sorted = (int*)alloc((size_t)NE * 4);
  int* eid_sorted = (int*)alloc((size_t)NE * 4);
  int* src32 = (int*)alloc((size_t)NE * 4);
  int* dst32 = (int*)alloc((size_t)NE * 4);
  int* flag = (int*)alloc(256);
  float* Wt[3]; float* bb[3]; float* Wt2[3];
  u16 *whi[3], *wlo[3];
  Wt[0] = (float*)alloc((size_t)NCOLS * 128 * 4);
  Wt[1] = (float*)alloc((size_t)NCOLS * 64 * 4);
  Wt[2] = (float*)alloc((size_t)NCOLS * 64 * 4);
  whi[0] = (u16*)alloc((size_t)NCOLS * 128 * 2);
  wlo[0] = (u16*)alloc((size_t)NCOLS * 128 * 2);
  whi[1] = (u16*)alloc((size_t)NCOLS * 64 * 2);
  wlo[1] = (u16*)alloc((size_t)NCOLS * 64 * 2);
  whi[2] = (u16*)alloc((size_t)NCOLS * 64 * 2);
  wlo[2] = (u16*)alloc((size_t)NCOLS * 64 * 2);
  for (int L = 0; L < 3; ++L) bb[L] = (float*)alloc((size_t)NCOLS * 4);
  for (int L = 0; L < 3; ++L) Wt2[L] = (float*)alloc((size_t)64 * 256 * 4);

  // Workspace overflow guard (all-zero output == error 1.65625 signature).
  if ((size_t)(p - (char*)d_ws) > ws_size) {
    hipMemsetAsync(d_out, 0, (size_t)out_size * 4, stream);
    return;
  }

  // Optional ea_csr buffer (205 MB).
  float* ea_csr = nullptr;
  int use_csr = 0;
  {
    size_t need = (size_t)(p - (char*)d_ws) + (size_t)NE * 64 * 4 + 256;
    if (need <= ws_size) {
      ea_csr = (float*)alloc((size_t)NE * 64 * 4);
      use_csr = 1;
    }
  }

  hipMemsetAsync(deg, 0, (size_t)NN * 4, stream);
  hipMemsetAsync(cursor, 0, (size_t)NN * 4, stream);
  hipMemsetAsync(flag, 0, 4, stream);

  detect_i64<<<8, 256, 0, stream>>>((const int*)ei, flag);
  extract_edges<<<2048, 256, 0, stream>>>(ei, flag, src32, dst32, NE);

  hist_kernel<<<2048, 256, 0, stream>>>(dst32, deg, NE);
  int nchunks = (NN + SCHUNK - 1) / SCHUNK;
  scanA<<<nchunks, SCHUNK, 0, stream>>>(deg, row_ptr, csum, NN);
  scanB<<<1, 64, 0, stream>>>(csum, nchunks);
  scanC<<<nchunks, SCHUNK, 0, stream>>>(row_ptr, csum, NN);
  scatter_kernel<<<2048, 256, 0, stream>>>(src32, dst32, row_ptr, cursor, src_sorted, eid_sorted, NE);
  sort_lists<<<(NN + 255) / 256, 256, 0, stream>>>(row_ptr, src_sorted, eid_sorted, NN);
  if (use_csr)
    ea_gather<<<2048, 256, 0, stream>>>(eid_sorted, ea, ea_csr, NE);

  cvt_split<<<2048, 256, 0, stream>>>(x, xhi, xlo, NN * 128);

  for (int L = 0; L < 3; ++L) {
    int fin = (L == 0) ? 128 : 64;
    prep_wt<<<(NCOLS * fin + 255) / 256, 256, 0, stream>>>(Wq[L], Wk[L], Wv[L], We[L], Wsk[L], Wt[L], fin);
    prep_bias<<<(NCOLS + 255) / 256, 256, 0, stream>>>(bq[L], bk[L], bv[L], We[L], bsk[L], bb[L]);
    prep_wpost<<<64, 256, 0, stream>>>(We[L], Wt2[L]);
    cvt_split<<<(NCOLS * fin + 255) / 256, 256, 0, stream>>>(Wt[L], whi[L], wlo[L], NCOLS * fin);
  }

  const u16* hi_in = xhi;
  const u16* lo_in = xlo;
  int nblk = (NN + 3) / 4;
  for (int L = 0; L < 3; ++L) {
    int fin = (L == 0) ? 128 : 64;
    dim3 g(17, (NN + 63) / 64);
    node_gemm_mfma<<<g, 256, 0, stream>>>(hi_in, lo_in, whi[L], wlo[L], bb[L],
                                          qq_tab, kv_tab, skip_tab, NN, fin);
    attn_kernel_v6<<<nblk, 256, 0, stream>>>(
        row_ptr, src_sorted, eid_sorted, ea, ea_csr, use_csr,
        qq_tab, kv_tab, avs_tab, awn_tab, NN);
    post_gn<<<(NN + 127) / 128, 256, 0, stream>>>(
        awn_tab, Wt2[L], avs_tab, skip_tab, gnw, gnb,
        (L == 2) ? (float*)d_out : nullptr,
        (L < 2) ? hhi : nullptr, (L < 2) ? hlo : nullptr, NN);
    hi_in = hhi; lo_in = hlo;
  }
}